// Round 1
// baseline (1381.651 us; speedup 1.0000x reference)
//
#include <hip/hip_runtime.h>
#include <stdint.h>

#define B 8
#define S 128
#define D 512
#define NIN 1024
#define NOUT 1024
#define T 32

// ---------------------------------------------------------------------------
// Generic fp32 tiled GEMM: C[M,N] = maybe_relu(A[M,K] @ Bm[K,N] + bias[N])
// 64x64 tile, BK=16, 256 threads, 4x4 micro-tile.
// ---------------------------------------------------------------------------
__global__ __launch_bounds__(256) void k_gemm(const float* __restrict__ A,
                                              const float* __restrict__ Bm,
                                              const float* __restrict__ bias,
                                              float* __restrict__ C,
                                              int M, int N, int K, int relu)
{
    __shared__ float As[16][64];
    __shared__ float Bs[16][64];
    const int tid = threadIdx.x;
    const int bx = blockIdx.x, by = blockIdx.y;
    const int tx = tid & 15, ty = tid >> 4;
    const int ar = tid >> 2, ak = (tid & 3) << 2;   // A tile: row 0..63, k 0..15 (x4)
    const int bk = tid >> 4, bc = (tid & 15) << 2;  // B tile: k 0..15, col 0..63 (x4)
    float acc[4][4] = {{0.f,0.f,0.f,0.f},{0.f,0.f,0.f,0.f},
                       {0.f,0.f,0.f,0.f},{0.f,0.f,0.f,0.f}};
    for (int k0 = 0; k0 < K; k0 += 16) {
        float4 a4 = *(const float4*)(A + (size_t)(by*64 + ar)*K + k0 + ak);
        float4 b4 = *(const float4*)(Bm + (size_t)(k0 + bk)*N + bx*64 + bc);
        __syncthreads();
        As[ak+0][ar] = a4.x; As[ak+1][ar] = a4.y;
        As[ak+2][ar] = a4.z; As[ak+3][ar] = a4.w;
        *(float4*)&Bs[bk][bc] = b4;
        __syncthreads();
        #pragma unroll
        for (int kk = 0; kk < 16; ++kk) {
            float4 av = *(const float4*)&As[kk][ty << 2];
            float4 bv = *(const float4*)&Bs[kk][tx << 2];
            acc[0][0] = fmaf(av.x, bv.x, acc[0][0]);
            acc[0][1] = fmaf(av.x, bv.y, acc[0][1]);
            acc[0][2] = fmaf(av.x, bv.z, acc[0][2]);
            acc[0][3] = fmaf(av.x, bv.w, acc[0][3]);
            acc[1][0] = fmaf(av.y, bv.x, acc[1][0]);
            acc[1][1] = fmaf(av.y, bv.y, acc[1][1]);
            acc[1][2] = fmaf(av.y, bv.z, acc[1][2]);
            acc[1][3] = fmaf(av.y, bv.w, acc[1][3]);
            acc[2][0] = fmaf(av.z, bv.x, acc[2][0]);
            acc[2][1] = fmaf(av.z, bv.y, acc[2][1]);
            acc[2][2] = fmaf(av.z, bv.z, acc[2][2]);
            acc[2][3] = fmaf(av.z, bv.w, acc[2][3]);
            acc[3][0] = fmaf(av.w, bv.x, acc[3][0]);
            acc[3][1] = fmaf(av.w, bv.y, acc[3][1]);
            acc[3][2] = fmaf(av.w, bv.z, acc[3][2]);
            acc[3][3] = fmaf(av.w, bv.w, acc[3][3]);
        }
    }
    const int row0 = by*64 + (ty << 2), col0 = bx*64 + (tx << 2);
    float4 bb = *(const float4*)(bias + col0);
    #pragma unroll
    for (int i = 0; i < 4; ++i) {
        float4 o;
        o.x = acc[i][0] + bb.x; o.y = acc[i][1] + bb.y;
        o.z = acc[i][2] + bb.z; o.w = acc[i][3] + bb.w;
        if (relu) {
            o.x = fmaxf(o.x, 0.f); o.y = fmaxf(o.y, 0.f);
            o.z = fmaxf(o.z, 0.f); o.w = fmaxf(o.w, 0.f);
        }
        *(float4*)(C + (size_t)(row0 + i)*N + col0) = o;
    }
}

// ---------------------------------------------------------------------------
// Input-population LIF: each thread = one (b, n_in) neuron, runs all 4096
// steps. Wave = 64 consecutive n of same b -> __ballot emits u64 spike mask.
// masks layout: [b][tg=0..4095][w=0..15] u64
// ---------------------------------------------------------------------------
__global__ __launch_bounds__(256) void k_lif_in(const float* __restrict__ snn,
                                                unsigned long long* __restrict__ masks,
                                                unsigned int* __restrict__ counters)
{
    const int tid  = blockIdx.x * 256 + threadIdx.x;  // 0..8191
    const int w    = tid >> 6;                        // wave 0..127
    const int lane = tid & 63;
    const int b    = w >> 4;
    const int nb   = w & 15;                          // u64-word index
    const int n    = (nb << 6) + lane;
    float v = 0.f;
    int cnt = 0;
    const float* cur = snn + (size_t)(b * S) * NIN + n;
    unsigned long long* mrow = masks + (size_t)(b * (S*T)) * 16 + nb;
    for (int s = 0; s < S; ++s) {
        const float I = cur[(size_t)s * NIN];
        #pragma unroll
        for (int t = 0; t < T; ++t) {
            v = __fadd_rn(__fmul_rn(0.9f, v), I);
            const bool sp = (v >= 1.0f);
            const unsigned long long m = __ballot(sp);
            v = sp ? (v - 1.0f) : v;
            cnt += sp ? 1 : 0;
            if (lane == 0) mrow[(size_t)(s*T + t) * 16] = m;
        }
    }
    atomicAdd(counters, (unsigned int)cnt);
}

// ---------------------------------------------------------------------------
// Spike-gather: block = one (b, position). Builds per-row 32-bit t-masks,
// then sums active W_conn rows into 32 float4 accumulators (all 1024 cols
// covered by 256 threads). Exact fp32, deterministic (n-ascending order).
// ---------------------------------------------------------------------------
__global__ __launch_bounds__(256, 2) void k_conn(const unsigned long long* __restrict__ masks,
                                                 const float* __restrict__ Wc,
                                                 float* __restrict__ Iout,
                                                 int s0, int P)
{
    const int idx = blockIdx.x;        // 0 .. B*P-1
    const int b = idx / P;
    const int sl = idx - b * P;
    const int s = s0 + sl;
    const int tid = threadIdx.x;
    const int Tc = P * T;

    __shared__ unsigned int tm[NIN];
    const unsigned long long* mbase = masks + (size_t)(b * (S*T) + s*T) * 16;
    #pragma unroll
    for (int i = 0; i < 4; ++i) {
        const int n = (tid << 2) + i;
        const int wq = n >> 6, bit = n & 63;
        unsigned int vmask = 0;
        #pragma unroll
        for (int t = 0; t < T; ++t)
            vmask |= (unsigned int)((mbase[t*16 + wq] >> bit) & 1ULL) << t;
        tm[n] = vmask;
    }
    __syncthreads();

    float4 acc[T];
    #pragma unroll
    for (int t = 0; t < T; ++t) acc[t] = make_float4(0.f, 0.f, 0.f, 0.f);

    const float* wp = Wc + (tid << 2);
    for (int n = 0; n < NIN; ++n) {
        const unsigned int m =
            (unsigned int)__builtin_amdgcn_readfirstlane((int)tm[n]);
        if (m == 0) continue;
        const float4 wv = *(const float4*)(wp + (size_t)n * NOUT);
        #pragma unroll
        for (int t = 0; t < T; ++t) {
            if (m & (1u << t)) {
                acc[t].x += wv.x; acc[t].y += wv.y;
                acc[t].z += wv.z; acc[t].w += wv.w;
            }
        }
    }

    float* obase = Iout + ((size_t)b * Tc + (size_t)sl * T) * NOUT + (tid << 2);
    #pragma unroll
    for (int t = 0; t < T; ++t)
        *(float4*)(obase + (size_t)t * NOUT) = acc[t];
}

// ---------------------------------------------------------------------------
// Output-population LIF: thread = one (b, n_out) neuron; walks the chunk's
// timesteps sequentially, accumulating per-position spike counts.
// ---------------------------------------------------------------------------
__global__ __launch_bounds__(256) void k_lif_out(const float* __restrict__ Iout,
                                                 float* __restrict__ vstate,
                                                 float* __restrict__ sacc_out,
                                                 unsigned int* __restrict__ counters,
                                                 int s0, int P, int init)
{
    const int tid = blockIdx.x * 256 + threadIdx.x;   // 0..8191
    const int b = tid >> 10, n = tid & (NOUT - 1);
    const int Tc = P * T;
    float v = init ? 0.f : vstate[tid];
    const float* ip = Iout + (size_t)b * Tc * NOUT + n;
    int cnt = 0;
    for (int sl = 0; sl < P; ++sl) {
        float sacc = 0.f;
        #pragma unroll
        for (int t = 0; t < T; ++t) {
            const float I = ip[(size_t)(sl*T + t) * NOUT];
            v = __fadd_rn(__fmul_rn(0.9f, v), I);
            const bool sp = (v >= 1.0f);
            v = sp ? (v - 1.0f) : v;
            sacc += sp ? 1.f : 0.f;
            cnt += sp ? 1 : 0;
        }
        sacc_out[(size_t)(b*S + s0 + sl) * NOUT + n] = sacc;
    }
    vstate[tid] = v;
    atomicAdd(counters + 1, (unsigned int)cnt);
}

__global__ void k_init(unsigned int* c)
{
    if (threadIdx.x < 2) c[threadIdx.x] = 0u;
}

__global__ void k_rate(const unsigned int* __restrict__ c, float* __restrict__ out)
{
    if (threadIdx.x == 0 && blockIdx.x == 0) {
        const float total = (float)c[0] + (float)c[1];
        out[0] = total / (float)(B * S * (NIN + NOUT) * T);
    }
}

// ---------------------------------------------------------------------------
extern "C" void kernel_launch(void* const* d_in, const int* in_sizes, int n_in,
                              void* d_out, int out_size, void* d_ws, size_t ws_size,
                              hipStream_t stream)
{
    const float* E    = (const float*)d_in[0];
    const float* Win  = (const float*)d_in[1];
    const float* bin  = (const float*)d_in[2];
    const float* Wc   = (const float*)d_in[3];
    const float* Wout = (const float*)d_in[4];
    const float* bout = (const float*)d_in[5];
    float* out = (float*)d_out;

    char* w = (char*)d_ws;
    float* snn              = (float*)(w);                          // 4 MB
    unsigned long long* msk = (unsigned long long*)(w + (4 << 20)); // 4 MB
    float* sacc             = (float*)(w + (8 << 20));              // 4 MB
    float* vst              = (float*)(w + (12 << 20));             // 32 KB
    unsigned int* cnt       = (unsigned int*)(w + (12 << 20) + (64 << 10));
    float* Iout             = (float*)(w + (13 << 20));

    const size_t base = (size_t)13 << 20;
    const size_t avail = (ws_size > base) ? (ws_size - base) : 0;
    int P = 1;
    if      (avail >= (size_t)B * 128 * T * NOUT * 4) P = 128;
    else if (avail >= (size_t)B *  16 * T * NOUT * 4) P = 16;
    else if (avail >= (size_t)B *   4 * T * NOUT * 4) P = 4;

    k_init<<<1, 64, 0, stream>>>(cnt);

    dim3 g1(NIN / 64, (B * S) / 64);
    k_gemm<<<g1, 256, 0, stream>>>(E, Win, bin, snn, B * S, NIN, D, 1);

    k_lif_in<<<32, 256, 0, stream>>>(snn, msk, cnt);

    for (int c = 0; c < S / P; ++c) {
        k_conn<<<B * P, 256, 0, stream>>>(msk, Wc, Iout, c * P, P);
        k_lif_out<<<32, 256, 0, stream>>>(Iout, vst, sacc, cnt, c * P, P, c == 0 ? 1 : 0);
    }

    dim3 g2(D / 64, (B * S) / 64);
    k_gemm<<<g2, 256, 0, stream>>>(sacc, Wout, bout, out, B * S, D, NOUT, 0);

    k_rate<<<1, 64, 0, stream>>>(cnt, out + (size_t)B * S * D);
}